// Round 18
// baseline (541.460 us; speedup 1.0000x reference)
//
#include <hip/hip_runtime.h>

#define N_NODES   100000
#define N_EDGES   1200000
#define D         64
#define N_GRAPHS  128
#define N_CLASSES 3

#define TILE      64                               // nodes per tile in layer
#define NTILES    ((N_NODES + TILE - 1) / TILE)    // 1563
#define CAPN1     16                               // hot row: one 64 B line/node
#define CAPN2     32                               // overflow row (deg<=48, P~3e-15)
#define LSTRIDE   68                               // 64 + 4 pad (floats)

#define NBKT      ((N_NODES + 255) / 256)          // 391 coarse buckets (dst>>8)
#define CCAP      3584                             // edges per bucket (mean 3072, >9 sigma)
#define EPB       8192                             // edges per binA block
#define NEB       ((N_EDGES + EPB - 1) / EPB)      // 147
#define GRID_PB   1024                             // prep+binA fused grid

typedef unsigned int  uint;
typedef unsigned short ushort;

// ------------------------------------------------------------- bf16 helpers
__device__ __forceinline__ ushort bf16_rne(float f) {
    uint u = __float_as_uint(f);
    u += 0x7FFFu + ((u >> 16) & 1u);      // round to nearest even
    return (ushort)(u >> 16);
}
__device__ __forceinline__ void acc8(float* a, uint4 v) {
    a[0] += __uint_as_float(v.x << 16);
    a[1] += __uint_as_float(v.x & 0xFFFF0000u);
    a[2] += __uint_as_float(v.y << 16);
    a[3] += __uint_as_float(v.y & 0xFFFF0000u);
    a[4] += __uint_as_float(v.z << 16);
    a[5] += __uint_as_float(v.z & 0xFFFF0000u);
    a[6] += __uint_as_float(v.w << 16);
    a[7] += __uint_as_float(v.w & 0xFFFF0000u);
}

// gather over one adjacency segment (unroll 8/4/1)
__device__ __forceinline__ void gather_seg(
        float* acc, const int* __restrict__ cp, int len,
        const ushort* __restrict__ hin, int fq8) {
    int j = 0;
    for (; j + 8 <= len; j += 8) {
        int s0 = cp[j + 0], s1 = cp[j + 1], s2 = cp[j + 2], s3 = cp[j + 3];
        int s4 = cp[j + 4], s5 = cp[j + 5], s6 = cp[j + 6], s7 = cp[j + 7];
        uint4 v0 = *(const uint4*)(hin + (size_t)s0 * D + fq8);
        uint4 v1 = *(const uint4*)(hin + (size_t)s1 * D + fq8);
        uint4 v2 = *(const uint4*)(hin + (size_t)s2 * D + fq8);
        uint4 v3 = *(const uint4*)(hin + (size_t)s3 * D + fq8);
        uint4 v4 = *(const uint4*)(hin + (size_t)s4 * D + fq8);
        uint4 v5 = *(const uint4*)(hin + (size_t)s5 * D + fq8);
        uint4 v6 = *(const uint4*)(hin + (size_t)s6 * D + fq8);
        uint4 v7 = *(const uint4*)(hin + (size_t)s7 * D + fq8);
        acc8(acc, v0); acc8(acc, v1); acc8(acc, v2); acc8(acc, v3);
        acc8(acc, v4); acc8(acc, v5); acc8(acc, v6); acc8(acc, v7);
    }
    for (; j + 4 <= len; j += 4) {
        int s0 = cp[j + 0], s1 = cp[j + 1], s2 = cp[j + 2], s3 = cp[j + 3];
        uint4 v0 = *(const uint4*)(hin + (size_t)s0 * D + fq8);
        uint4 v1 = *(const uint4*)(hin + (size_t)s1 * D + fq8);
        uint4 v2 = *(const uint4*)(hin + (size_t)s2 * D + fq8);
        uint4 v3 = *(const uint4*)(hin + (size_t)s3 * D + fq8);
        acc8(acc, v0); acc8(acc, v1); acc8(acc, v2); acc8(acc, v3);
    }
    for (; j < len; ++j) {
        uint4 v = *(const uint4*)(hin + (size_t)cp[j] * D + fq8);
        acc8(acc, v);
    }
}

// ---------- fused prep + binA:
// blocks [0,NEB): coarse partition by dst>>8 (packed: src | (dst&255)<<17)
// blocks [NEB,GRID_PB): x f32->bf16 convert
// (g/gcur zeroing is done by hipMemsetAsync before this kernel)
__global__ __launch_bounds__(256) void prep_binA_kernel(
        const float* __restrict__ x, ushort* __restrict__ Xb,
        const int* __restrict__ src, const int* __restrict__ dst,
        int* __restrict__ gcur, int* __restrict__ cbuf) {
    __shared__ int hist[NBKT];
    __shared__ int pos[NBKT];
    const int tid = threadIdx.x;
    const int bid = blockIdx.x;

    if (bid < NEB) {
        const int e0 = bid * EPB;
        int e1 = e0 + EPB; if (e1 > N_EDGES) e1 = N_EDGES;
        for (int i = tid; i < NBKT; i += 256) hist[i] = 0;
        __syncthreads();
        for (int e = e0 + tid; e < e1; e += 256)
            atomicAdd(&hist[dst[e] >> 8], 1);
        __syncthreads();
        for (int b = tid; b < NBKT; b += 256)
            pos[b] = hist[b] ? atomicAdd(&gcur[b], hist[b]) : 0;
        __syncthreads();
        for (int e = e0 + tid; e < e1; e += 256) {
            int d = dst[e];
            int b = d >> 8;
            int r = atomicAdd(&pos[b], 1);
            if (r < CCAP) cbuf[b * CCAP + r] = src[e] | ((d & 255) << 17);
        }
    } else {
        const int cb  = bid - NEB;
        const int NCB = GRID_PB - NEB;       // 877 convert blocks
        const int nodeF4 = N_NODES * D / 4;
        for (int i = cb * 256 + tid; i < nodeF4; i += NCB * 256) {
            float4 v = ((const float4*)x)[i];
            ushort4 o;
            o.x = bf16_rne(v.x); o.y = bf16_rne(v.y);
            o.z = bf16_rne(v.z); o.w = bf16_rne(v.w);
            ((ushort4*)Xb)[i] = o;
        }
    }
}

// ---------- binB: per-bucket scatter into padded per-node rows.
__global__ __launch_bounds__(256) void binB_kernel(
        const int* __restrict__ cbuf, const int* __restrict__ gcur,
        int* __restrict__ b1, int* __restrict__ b2, int* __restrict__ cnt) {
    __shared__ int ldeg[256];
    const int bkt   = blockIdx.x;
    const int tid   = threadIdx.x;
    const int base  = bkt * CCAP;
    const int node0 = bkt << 8;

    int E = gcur[bkt]; if (E > CCAP) E = CCAP;
    ldeg[tid] = 0;
    __syncthreads();

    for (int i = tid; i < E; i += 256) {
        int p  = cbuf[base + i];
        int ld = (p >> 17) & 255;
        int s  = p & 0x1FFFF;
        int c  = atomicAdd(&ldeg[ld], 1);
        int n  = node0 + ld;
        if (c < CAPN1) b1[n * CAPN1 + c] = s;
        else if (c < CAPN1 + CAPN2) b2[n * CAPN2 + (c - CAPN1)] = s;
    }
    __syncthreads();
    int n = node0 + tid;
    if (n < N_NODES) cnt[n] = ldeg[tid];
}

// --------------------------- fused layer: gather + agg@Wr + h@Ws + br, relu
// TILE=64, 2-round gather unroll-8, LDS aggS only (17.4 KB).
// launch_bounds(256,6): 85-VGPR cap (measured demand 52 -> no spill),
// 6 blocks/CU = 24 waves/CU (LDS 6*17.9=107 KB < 160 KB).
template<int DO_POOL>
__global__ __launch_bounds__(256, 6) void fused_layer_kernel(
        const ushort* __restrict__ hin,
        const int* __restrict__ cnt,
        const int* __restrict__ b1,
        const int* __restrict__ b2,
        const float* __restrict__ Wr,
        const float* __restrict__ br,
        const float* __restrict__ Ws,
        ushort* __restrict__ hout,
        const int* __restrict__ batch,
        float* __restrict__ g) {
    __shared__ float aggS[TILE * LSTRIDE];   // 17.4 KB
    __shared__ int   bS[TILE];

    const int tid   = threadIdx.x;
    const int node0 = blockIdx.x * TILE;

    if (DO_POOL && tid < TILE) {
        int n = node0 + tid;
        bS[tid] = (n < N_NODES) ? batch[n] : -1;
    }

    // ---- gather: 2 rounds x 32 nodes; thread = (node-slot, 16B slice of 8 feats)
    const int fq8 = (tid & 7) * 8;
    for (int r = 0; r < 2; ++r) {
        int ln = r * 32 + (tid >> 3);
        int n  = node0 + ln;
        float acc[8] = {0.f, 0.f, 0.f, 0.f, 0.f, 0.f, 0.f, 0.f};
        if (n < N_NODES) {
            int deg = cnt[n];
            if (deg > CAPN1 + CAPN2) deg = CAPN1 + CAPN2;
            int d1 = deg < CAPN1 ? deg : CAPN1;
            gather_seg(acc, b1 + n * CAPN1, d1, hin, fq8);
            if (deg > CAPN1)
                gather_seg(acc, b2 + n * CAPN2, deg - CAPN1, hin, fq8);
        }
        *(float4*)&aggS[ln * LSTRIDE + fq8]     = make_float4(acc[0], acc[1], acc[2], acc[3]);
        *(float4*)&aggS[ln * LSTRIDE + fq8 + 4] = make_float4(acc[4], acc[5], acc[6], acc[7]);
    }
    __syncthreads();

    // ---- GEMM: thread = (node-quad q, feature-quad fq)
    const int q  = tid >> 4;
    const int fq = tid & 15;
    const int f4 = fq * 4;
    const int n0 = node0 + 4 * q;
    const float4* Wr4 = (const float4*)Wr;   // Wr4[k*16+fq]
    const float4* Ws4 = (const float4*)Ws;
    const uint* x0p = (const uint*)(hin + (size_t)(n0 + 0) * D);
    const uint* x1p = (const uint*)(hin + (size_t)(n0 + 1) * D);
    const uint* x2p = (const uint*)(hin + (size_t)(n0 + 2) * D);
    const uint* x3p = (const uint*)(hin + (size_t)(n0 + 3) * D);
    float4 bias = *(const float4*)(br + f4);
    float4 c0 = bias, c1 = bias, c2 = bias, c3 = bias;

#pragma unroll 4
    for (int kk = 0; kk < 32; ++kk) {
        const int k0 = 2 * kk;
        float4 wrA = Wr4[k0 * 16 + fq];
        float4 wrB = Wr4[(k0 + 1) * 16 + fq];
        float4 wsA = Ws4[k0 * 16 + fq];
        float4 wsB = Ws4[(k0 + 1) * 16 + fq];
        uint u0 = x0p[kk], u1 = x1p[kk], u2 = x2p[kk], u3 = x3p[kk];
        float2 a0 = *(const float2*)&aggS[(4 * q + 0) * LSTRIDE + k0];
        float2 a1 = *(const float2*)&aggS[(4 * q + 1) * LSTRIDE + k0];
        float2 a2 = *(const float2*)&aggS[(4 * q + 2) * LSTRIDE + k0];
        float2 a3 = *(const float2*)&aggS[(4 * q + 3) * LSTRIDE + k0];
        float x0A = __uint_as_float(u0 << 16), x0B = __uint_as_float(u0 & 0xFFFF0000u);
        float x1A = __uint_as_float(u1 << 16), x1B = __uint_as_float(u1 & 0xFFFF0000u);
        float x2A = __uint_as_float(u2 << 16), x2B = __uint_as_float(u2 & 0xFFFF0000u);
        float x3A = __uint_as_float(u3 << 16), x3B = __uint_as_float(u3 & 0xFFFF0000u);
        c0.x += a0.x * wrA.x + x0A * wsA.x;  c0.y += a0.x * wrA.y + x0A * wsA.y;
        c0.z += a0.x * wrA.z + x0A * wsA.z;  c0.w += a0.x * wrA.w + x0A * wsA.w;
        c0.x += a0.y * wrB.x + x0B * wsB.x;  c0.y += a0.y * wrB.y + x0B * wsB.y;
        c0.z += a0.y * wrB.z + x0B * wsB.z;  c0.w += a0.y * wrB.w + x0B * wsB.w;
        c1.x += a1.x * wrA.x + x1A * wsA.x;  c1.y += a1.x * wrA.y + x1A * wsA.y;
        c1.z += a1.x * wrA.z + x1A * wsA.z;  c1.w += a1.x * wrA.w + x1A * wsA.w;
        c1.x += a1.y * wrB.x + x1B * wsB.x;  c1.y += a1.y * wrB.y + x1B * wsB.y;
        c1.z += a1.y * wrB.z + x1B * wsB.z;  c1.w += a1.y * wrB.w + x1B * wsB.w;
        c2.x += a2.x * wrA.x + x2A * wsA.x;  c2.y += a2.x * wrA.y + x2A * wsA.y;
        c2.z += a2.x * wrA.z + x2A * wsA.z;  c2.w += a2.x * wrA.w + x2A * wsA.w;
        c2.x += a2.y * wrB.x + x2B * wsB.x;  c2.y += a2.y * wrB.y + x2B * wsB.y;
        c2.z += a2.y * wrB.z + x2B * wsB.z;  c2.w += a2.y * wrB.w + x2B * wsB.w;
        c3.x += a3.x * wrA.x + x3A * wsA.x;  c3.y += a3.x * wrA.y + x3A * wsA.y;
        c3.z += a3.x * wrA.z + x3A * wsA.z;  c3.w += a3.x * wrA.w + x3A * wsA.w;
        c3.x += a3.y * wrB.x + x3B * wsB.x;  c3.y += a3.y * wrB.y + x3B * wsB.y;
        c3.z += a3.y * wrB.z + x3B * wsB.z;  c3.w += a3.y * wrB.w + x3B * wsB.w;
    }

    float4 cc[4] = {c0, c1, c2, c3};

    if (!DO_POOL) {
#pragma unroll
        for (int i = 0; i < 4; ++i) {
            int n = node0 + 4 * q + i;
            if (n < N_NODES) {
                ushort4 o;
                o.x = bf16_rne(fmaxf(cc[i].x, 0.f));
                o.y = bf16_rne(fmaxf(cc[i].y, 0.f));
                o.z = bf16_rne(fmaxf(cc[i].z, 0.f));
                o.w = bf16_rne(fmaxf(cc[i].w, 0.f));
                *(ushort4*)(hout + (size_t)n * D + f4) = o;
            }
        }
    } else {
        __syncthreads();   // everyone done reading aggS
#pragma unroll
        for (int i = 0; i < 4; ++i) {
            float* a = &aggS[(4 * q + i) * LSTRIDE + f4];
            a[0] = fmaxf(cc[i].x, 0.f);
            a[1] = fmaxf(cc[i].y, 0.f);
            a[2] = fmaxf(cc[i].z, 0.f);
            a[3] = fmaxf(cc[i].w, 0.f);
        }
        __syncthreads();
        int f    = tid & 63;
        int part = tid >> 6;
        int ln0  = part * 16;
        int cur  = bS[ln0];
        float acc = 0.f;
        for (int ln = ln0; ln < ln0 + 16; ++ln) {
            int b = bS[ln];
            if (b < 0) break;
            if (b != cur) {
                atomicAdd(&g[cur * D + f], acc);
                acc = 0.f;
                cur = b;
            }
            acc += aggS[ln * LSTRIDE + f];
        }
        if (cur >= 0) atomicAdd(&g[cur * D + f], acc);
    }
}

// ------------------------------------------------------------------- MLP head
__global__ __launch_bounds__(64) void head_kernel(
        const float* __restrict__ g,
        const float* __restrict__ Wfc1, const float* __restrict__ bfc1,
        const float* __restrict__ Wfc2, const float* __restrict__ bfc2,
        float* __restrict__ out) {
    __shared__ float hS[D];
    __shared__ float lS[N_CLASSES];
    int gr = blockIdx.x;
    int f  = threadIdx.x;

    float acc = bfc1[f];
#pragma unroll
    for (int k = 0; k < D; ++k) acc += g[gr * D + k] * Wfc1[k * D + f];
    hS[f] = fmaxf(acc, 0.f);
    __syncthreads();

    if (f < N_CLASSES) {
        float a = bfc2[f];
#pragma unroll
        for (int k = 0; k < D; ++k) a += hS[k] * Wfc2[k * N_CLASSES + f];
        lS[f] = a;
    }
    __syncthreads();

    if (f == 0) {
        float m = fmaxf(lS[0], fmaxf(lS[1], lS[2]));
        float s = expf(lS[0] - m) + expf(lS[1] - m) + expf(lS[2] - m);
        float lse = m + logf(s);
        out[gr * 3 + 0] = lS[0] - lse;
        out[gr * 3 + 1] = lS[1] - lse;
        out[gr * 3 + 2] = lS[2] - lse;
    }
}

// ---------------------------------------------------------------------- launch
extern "C" void kernel_launch(void* const* d_in, const int* in_sizes, int n_in,
                              void* d_out, int out_size, void* d_ws, size_t ws_size,
                              hipStream_t stream) {
    const float* x     = (const float*)d_in[0];
    const int*   edge  = (const int*)d_in[1];
    const int*   batch = (const int*)d_in[2];
    const float* Wr1 = (const float*)d_in[3];
    const float* br1 = (const float*)d_in[4];
    const float* Ws1 = (const float*)d_in[5];
    const float* Wr2 = (const float*)d_in[6];
    const float* br2 = (const float*)d_in[7];
    const float* Ws2 = (const float*)d_in[8];
    const float* Wr3 = (const float*)d_in[9];
    const float* br3 = (const float*)d_in[10];
    const float* Ws3 = (const float*)d_in[11];
    const float* Wfc1 = (const float*)d_in[12];
    const float* bfc1 = (const float*)d_in[13];
    const float* Wfc2 = (const float*)d_in[14];
    const float* bfc2 = (const float*)d_in[15];

    const int* src = edge;
    const int* dst = edge + N_EDGES;

    // workspace layout (16 B aligned), ~51 MB total
    ushort* Xb     = (ushort*)d_ws;                       // 6.4M bf16 (12.8 MB)
    ushort* Ab     = Xb + (size_t)N_NODES * D;            // 6.4M bf16 (12.8 MB)
    float*  g      = (float*)(Ab + (size_t)N_NODES * D);  // 8192 f
    int*   gcur    = (int*)(g + (size_t)N_GRAPHS * D);    // 392 i
    int*   cnt     = gcur + 392;                          // 100,000 i (binB writes)
    int*   b1      = cnt + N_NODES;                       // 100,000*16 i (6.4 MB)
    int*   b2      = b1 + (size_t)N_NODES * CAPN1;        // 100,000*32 i (12.8 MB)
    int*   cbuf    = b2 + (size_t)N_NODES * CAPN2;        // 391*3584 i (5.6 MB)

    dim3 blk256(256);
    dim3 grdB((int)NBKT);                                 // 391
    dim3 grdT((int)NTILES);                               // 1563

    // ---- zero g + gcur via graph-capturable DMA memset (34.3 KB)
    hipMemsetAsync(g, 0, (size_t)(N_GRAPHS * D + 392) * sizeof(float), stream);

    // ---- fused prep(x->bf16) + binA coarse partition
    prep_binA_kernel<<<dim3(GRID_PB), blk256, 0, stream>>>(x, Xb, src, dst, gcur, cbuf);

    // ---- binB: per-bucket dense scatter
    binB_kernel<<<grdB, blk256, 0, stream>>>(cbuf, gcur, b1, b2, cnt);

    // ---- 3 fused GraphConv layers (layer 3 pools directly into g)
    fused_layer_kernel<0><<<grdT, blk256, 0, stream>>>(Xb, cnt, b1, b2, Wr1, br1, Ws1, Ab, batch, g);
    fused_layer_kernel<0><<<grdT, blk256, 0, stream>>>(Ab, cnt, b1, b2, Wr2, br2, Ws2, Xb, batch, g);
    fused_layer_kernel<1><<<grdT, blk256, 0, stream>>>(Xb, cnt, b1, b2, Wr3, br3, Ws3, Ab, batch, g);

    // ---- head
    head_kernel<<<dim3(N_GRAPHS), dim3(64), 0, stream>>>(g, Wfc1, bfc1, Wfc2, bfc2, (float*)d_out);
}

// Round 19
// 334.840 us; speedup vs baseline: 1.6171x; 1.6171x over previous
//
#include <hip/hip_runtime.h>

#define N_NODES   100000
#define N_EDGES   1200000
#define D         64
#define N_GRAPHS  128
#define N_CLASSES 3

#define TILE      64                               // nodes per tile in layer
#define NTILES    ((N_NODES + TILE - 1) / TILE)    // 1563
#define CAPN1     16                               // hot row: one 64 B line/node
#define CAPN2     32                               // overflow row (deg<=48, P~3e-15)
#define LSTRIDE   68                               // 64 + 4 pad (floats)

#define NBKT      ((N_NODES + 255) / 256)          // 391 coarse buckets (dst>>8)
#define CCAP      3584                             // edges per bucket (mean 3072, >9 sigma)
#define EPB       8192                             // edges per binA block
#define NEB       ((N_EDGES + EPB - 1) / EPB)      // 147
#define GRID_PB   1024                             // prep+binA fused grid

typedef unsigned int  uint;
typedef unsigned short ushort;

// ------------------------------------------------------------- bf16 helpers
__device__ __forceinline__ ushort bf16_rne(float f) {
    uint u = __float_as_uint(f);
    u += 0x7FFFu + ((u >> 16) & 1u);      // round to nearest even
    return (ushort)(u >> 16);
}
__device__ __forceinline__ void acc8(float* a, uint4 v) {
    a[0] += __uint_as_float(v.x << 16);
    a[1] += __uint_as_float(v.x & 0xFFFF0000u);
    a[2] += __uint_as_float(v.y << 16);
    a[3] += __uint_as_float(v.y & 0xFFFF0000u);
    a[4] += __uint_as_float(v.z << 16);
    a[5] += __uint_as_float(v.z & 0xFFFF0000u);
    a[6] += __uint_as_float(v.w << 16);
    a[7] += __uint_as_float(v.w & 0xFFFF0000u);
}

// gather over one adjacency segment (unroll 8/4/1)
__device__ __forceinline__ void gather_seg(
        float* acc, const int* __restrict__ cp, int len,
        const ushort* __restrict__ hin, int fq8) {
    int j = 0;
    for (; j + 8 <= len; j += 8) {
        int s0 = cp[j + 0], s1 = cp[j + 1], s2 = cp[j + 2], s3 = cp[j + 3];
        int s4 = cp[j + 4], s5 = cp[j + 5], s6 = cp[j + 6], s7 = cp[j + 7];
        uint4 v0 = *(const uint4*)(hin + (size_t)s0 * D + fq8);
        uint4 v1 = *(const uint4*)(hin + (size_t)s1 * D + fq8);
        uint4 v2 = *(const uint4*)(hin + (size_t)s2 * D + fq8);
        uint4 v3 = *(const uint4*)(hin + (size_t)s3 * D + fq8);
        uint4 v4 = *(const uint4*)(hin + (size_t)s4 * D + fq8);
        uint4 v5 = *(const uint4*)(hin + (size_t)s5 * D + fq8);
        uint4 v6 = *(const uint4*)(hin + (size_t)s6 * D + fq8);
        uint4 v7 = *(const uint4*)(hin + (size_t)s7 * D + fq8);
        acc8(acc, v0); acc8(acc, v1); acc8(acc, v2); acc8(acc, v3);
        acc8(acc, v4); acc8(acc, v5); acc8(acc, v6); acc8(acc, v7);
    }
    for (; j + 4 <= len; j += 4) {
        int s0 = cp[j + 0], s1 = cp[j + 1], s2 = cp[j + 2], s3 = cp[j + 3];
        uint4 v0 = *(const uint4*)(hin + (size_t)s0 * D + fq8);
        uint4 v1 = *(const uint4*)(hin + (size_t)s1 * D + fq8);
        uint4 v2 = *(const uint4*)(hin + (size_t)s2 * D + fq8);
        uint4 v3 = *(const uint4*)(hin + (size_t)s3 * D + fq8);
        acc8(acc, v0); acc8(acc, v1); acc8(acc, v2); acc8(acc, v3);
    }
    for (; j < len; ++j) {
        uint4 v = *(const uint4*)(hin + (size_t)cp[j] * D + fq8);
        acc8(acc, v);
    }
}

// ---------- fused prep + binA:
// blocks [0,NEB): coarse partition by dst>>8 (packed: src | (dst&255)<<17)
// blocks [NEB,GRID_PB): x f32->bf16 convert
// (g/gcur zeroing is done by hipMemsetAsync before this kernel)
__global__ __launch_bounds__(256) void prep_binA_kernel(
        const float* __restrict__ x, ushort* __restrict__ Xb,
        const int* __restrict__ src, const int* __restrict__ dst,
        int* __restrict__ gcur, int* __restrict__ cbuf) {
    __shared__ int hist[NBKT];
    __shared__ int pos[NBKT];
    const int tid = threadIdx.x;
    const int bid = blockIdx.x;

    if (bid < NEB) {
        const int e0 = bid * EPB;
        int e1 = e0 + EPB; if (e1 > N_EDGES) e1 = N_EDGES;
        for (int i = tid; i < NBKT; i += 256) hist[i] = 0;
        __syncthreads();
        for (int e = e0 + tid; e < e1; e += 256)
            atomicAdd(&hist[dst[e] >> 8], 1);
        __syncthreads();
        for (int b = tid; b < NBKT; b += 256)
            pos[b] = hist[b] ? atomicAdd(&gcur[b], hist[b]) : 0;
        __syncthreads();
        for (int e = e0 + tid; e < e1; e += 256) {
            int d = dst[e];
            int b = d >> 8;
            int r = atomicAdd(&pos[b], 1);
            if (r < CCAP) cbuf[b * CCAP + r] = src[e] | ((d & 255) << 17);
        }
    } else {
        const int cb  = bid - NEB;
        const int NCB = GRID_PB - NEB;       // 877 convert blocks
        const int nodeF4 = N_NODES * D / 4;
        for (int i = cb * 256 + tid; i < nodeF4; i += NCB * 256) {
            float4 v = ((const float4*)x)[i];
            ushort4 o;
            o.x = bf16_rne(v.x); o.y = bf16_rne(v.y);
            o.z = bf16_rne(v.z); o.w = bf16_rne(v.w);
            ((ushort4*)Xb)[i] = o;
        }
    }
}

// ---------- binB: per-bucket scatter into padded per-node rows.
__global__ __launch_bounds__(256) void binB_kernel(
        const int* __restrict__ cbuf, const int* __restrict__ gcur,
        int* __restrict__ b1, int* __restrict__ b2, int* __restrict__ cnt) {
    __shared__ int ldeg[256];
    const int bkt   = blockIdx.x;
    const int tid   = threadIdx.x;
    const int base  = bkt * CCAP;
    const int node0 = bkt << 8;

    int E = gcur[bkt]; if (E > CCAP) E = CCAP;
    ldeg[tid] = 0;
    __syncthreads();

    for (int i = tid; i < E; i += 256) {
        int p  = cbuf[base + i];
        int ld = (p >> 17) & 255;
        int s  = p & 0x1FFFF;
        int c  = atomicAdd(&ldeg[ld], 1);
        int n  = node0 + ld;
        if (c < CAPN1) b1[n * CAPN1 + c] = s;
        else if (c < CAPN1 + CAPN2) b2[n * CAPN2 + (c - CAPN1)] = s;
    }
    __syncthreads();
    int n = node0 + tid;
    if (n < N_NODES) cnt[n] = ldeg[tid];
}

// --------------------------- fused layer: gather + agg@Wr + h@Ws + br, relu
// TILE=64, 2-round gather unroll-8, LDS aggS only (17.4 KB).
// launch_bounds(256,4): PROVEN no-spill point (52 VGPR). (256,6) and (256,8)
// both force allocator below demand -> scratch spill (R8, R18). Do not raise.
template<int DO_POOL>
__global__ __launch_bounds__(256, 4) void fused_layer_kernel(
        const ushort* __restrict__ hin,
        const int* __restrict__ cnt,
        const int* __restrict__ b1,
        const int* __restrict__ b2,
        const float* __restrict__ Wr,
        const float* __restrict__ br,
        const float* __restrict__ Ws,
        ushort* __restrict__ hout,
        const int* __restrict__ batch,
        float* __restrict__ g) {
    __shared__ float aggS[TILE * LSTRIDE];   // 17.4 KB
    __shared__ int   bS[TILE];

    const int tid   = threadIdx.x;
    const int node0 = blockIdx.x * TILE;

    if (DO_POOL && tid < TILE) {
        int n = node0 + tid;
        bS[tid] = (n < N_NODES) ? batch[n] : -1;
    }

    // ---- gather: 2 rounds x 32 nodes; thread = (node-slot, 16B slice of 8 feats)
    const int fq8 = (tid & 7) * 8;
    for (int r = 0; r < 2; ++r) {
        int ln = r * 32 + (tid >> 3);
        int n  = node0 + ln;
        float acc[8] = {0.f, 0.f, 0.f, 0.f, 0.f, 0.f, 0.f, 0.f};
        if (n < N_NODES) {
            int deg = cnt[n];
            if (deg > CAPN1 + CAPN2) deg = CAPN1 + CAPN2;
            int d1 = deg < CAPN1 ? deg : CAPN1;
            gather_seg(acc, b1 + n * CAPN1, d1, hin, fq8);
            if (deg > CAPN1)
                gather_seg(acc, b2 + n * CAPN2, deg - CAPN1, hin, fq8);
        }
        *(float4*)&aggS[ln * LSTRIDE + fq8]     = make_float4(acc[0], acc[1], acc[2], acc[3]);
        *(float4*)&aggS[ln * LSTRIDE + fq8 + 4] = make_float4(acc[4], acc[5], acc[6], acc[7]);
    }
    __syncthreads();

    // ---- GEMM: thread = (node-quad q, feature-quad fq)
    const int q  = tid >> 4;
    const int fq = tid & 15;
    const int f4 = fq * 4;
    const int n0 = node0 + 4 * q;
    const float4* Wr4 = (const float4*)Wr;   // Wr4[k*16+fq]
    const float4* Ws4 = (const float4*)Ws;
    const uint* x0p = (const uint*)(hin + (size_t)(n0 + 0) * D);
    const uint* x1p = (const uint*)(hin + (size_t)(n0 + 1) * D);
    const uint* x2p = (const uint*)(hin + (size_t)(n0 + 2) * D);
    const uint* x3p = (const uint*)(hin + (size_t)(n0 + 3) * D);
    float4 bias = *(const float4*)(br + f4);
    float4 c0 = bias, c1 = bias, c2 = bias, c3 = bias;

#pragma unroll 4
    for (int kk = 0; kk < 32; ++kk) {
        const int k0 = 2 * kk;
        float4 wrA = Wr4[k0 * 16 + fq];
        float4 wrB = Wr4[(k0 + 1) * 16 + fq];
        float4 wsA = Ws4[k0 * 16 + fq];
        float4 wsB = Ws4[(k0 + 1) * 16 + fq];
        uint u0 = x0p[kk], u1 = x1p[kk], u2 = x2p[kk], u3 = x3p[kk];
        float2 a0 = *(const float2*)&aggS[(4 * q + 0) * LSTRIDE + k0];
        float2 a1 = *(const float2*)&aggS[(4 * q + 1) * LSTRIDE + k0];
        float2 a2 = *(const float2*)&aggS[(4 * q + 2) * LSTRIDE + k0];
        float2 a3 = *(const float2*)&aggS[(4 * q + 3) * LSTRIDE + k0];
        float x0A = __uint_as_float(u0 << 16), x0B = __uint_as_float(u0 & 0xFFFF0000u);
        float x1A = __uint_as_float(u1 << 16), x1B = __uint_as_float(u1 & 0xFFFF0000u);
        float x2A = __uint_as_float(u2 << 16), x2B = __uint_as_float(u2 & 0xFFFF0000u);
        float x3A = __uint_as_float(u3 << 16), x3B = __uint_as_float(u3 & 0xFFFF0000u);
        c0.x += a0.x * wrA.x + x0A * wsA.x;  c0.y += a0.x * wrA.y + x0A * wsA.y;
        c0.z += a0.x * wrA.z + x0A * wsA.z;  c0.w += a0.x * wrA.w + x0A * wsA.w;
        c0.x += a0.y * wrB.x + x0B * wsB.x;  c0.y += a0.y * wrB.y + x0B * wsB.y;
        c0.z += a0.y * wrB.z + x0B * wsB.z;  c0.w += a0.y * wrB.w + x0B * wsB.w;
        c1.x += a1.x * wrA.x + x1A * wsA.x;  c1.y += a1.x * wrA.y + x1A * wsA.y;
        c1.z += a1.x * wrA.z + x1A * wsA.z;  c1.w += a1.x * wrA.w + x1A * wsA.w;
        c1.x += a1.y * wrB.x + x1B * wsB.x;  c1.y += a1.y * wrB.y + x1B * wsB.y;
        c1.z += a1.y * wrB.z + x1B * wsB.z;  c1.w += a1.y * wrB.w + x1B * wsB.w;
        c2.x += a2.x * wrA.x + x2A * wsA.x;  c2.y += a2.x * wrA.y + x2A * wsA.y;
        c2.z += a2.x * wrA.z + x2A * wsA.z;  c2.w += a2.x * wrA.w + x2A * wsA.w;
        c2.x += a2.y * wrB.x + x2B * wsB.x;  c2.y += a2.y * wrB.y + x2B * wsB.y;
        c2.z += a2.y * wrB.z + x2B * wsB.z;  c2.w += a2.y * wrB.w + x2B * wsB.w;
        c3.x += a3.x * wrA.x + x3A * wsA.x;  c3.y += a3.x * wrA.y + x3A * wsA.y;
        c3.z += a3.x * wrA.z + x3A * wsA.z;  c3.w += a3.x * wrA.w + x3A * wsA.w;
        c3.x += a3.y * wrB.x + x3B * wsB.x;  c3.y += a3.y * wrB.y + x3B * wsB.y;
        c3.z += a3.y * wrB.z + x3B * wsB.z;  c3.w += a3.y * wrB.w + x3B * wsB.w;
    }

    float4 cc[4] = {c0, c1, c2, c3};

    if (!DO_POOL) {
#pragma unroll
        for (int i = 0; i < 4; ++i) {
            int n = node0 + 4 * q + i;
            if (n < N_NODES) {
                ushort4 o;
                o.x = bf16_rne(fmaxf(cc[i].x, 0.f));
                o.y = bf16_rne(fmaxf(cc[i].y, 0.f));
                o.z = bf16_rne(fmaxf(cc[i].z, 0.f));
                o.w = bf16_rne(fmaxf(cc[i].w, 0.f));
                *(ushort4*)(hout + (size_t)n * D + f4) = o;
            }
        }
    } else {
        __syncthreads();   // everyone done reading aggS
#pragma unroll
        for (int i = 0; i < 4; ++i) {
            float* a = &aggS[(4 * q + i) * LSTRIDE + f4];
            a[0] = fmaxf(cc[i].x, 0.f);
            a[1] = fmaxf(cc[i].y, 0.f);
            a[2] = fmaxf(cc[i].z, 0.f);
            a[3] = fmaxf(cc[i].w, 0.f);
        }
        __syncthreads();
        int f    = tid & 63;
        int part = tid >> 6;
        int ln0  = part * 16;
        int cur  = bS[ln0];
        float acc = 0.f;
        for (int ln = ln0; ln < ln0 + 16; ++ln) {
            int b = bS[ln];
            if (b < 0) break;
            if (b != cur) {
                atomicAdd(&g[cur * D + f], acc);
                acc = 0.f;
                cur = b;
            }
            acc += aggS[ln * LSTRIDE + f];
        }
        if (cur >= 0) atomicAdd(&g[cur * D + f], acc);
    }
}

// ------------------------------------------------------------------- MLP head
__global__ __launch_bounds__(64) void head_kernel(
        const float* __restrict__ g,
        const float* __restrict__ Wfc1, const float* __restrict__ bfc1,
        const float* __restrict__ Wfc2, const float* __restrict__ bfc2,
        float* __restrict__ out) {
    __shared__ float hS[D];
    __shared__ float lS[N_CLASSES];
    int gr = blockIdx.x;
    int f  = threadIdx.x;

    float acc = bfc1[f];
#pragma unroll
    for (int k = 0; k < D; ++k) acc += g[gr * D + k] * Wfc1[k * D + f];
    hS[f] = fmaxf(acc, 0.f);
    __syncthreads();

    if (f < N_CLASSES) {
        float a = bfc2[f];
#pragma unroll
        for (int k = 0; k < D; ++k) a += hS[k] * Wfc2[k * N_CLASSES + f];
        lS[f] = a;
    }
    __syncthreads();

    if (f == 0) {
        float m = fmaxf(lS[0], fmaxf(lS[1], lS[2]));
        float s = expf(lS[0] - m) + expf(lS[1] - m) + expf(lS[2] - m);
        float lse = m + logf(s);
        out[gr * 3 + 0] = lS[0] - lse;
        out[gr * 3 + 1] = lS[1] - lse;
        out[gr * 3 + 2] = lS[2] - lse;
    }
}

// ---------------------------------------------------------------------- launch
extern "C" void kernel_launch(void* const* d_in, const int* in_sizes, int n_in,
                              void* d_out, int out_size, void* d_ws, size_t ws_size,
                              hipStream_t stream) {
    const float* x     = (const float*)d_in[0];
    const int*   edge  = (const int*)d_in[1];
    const int*   batch = (const int*)d_in[2];
    const float* Wr1 = (const float*)d_in[3];
    const float* br1 = (const float*)d_in[4];
    const float* Ws1 = (const float*)d_in[5];
    const float* Wr2 = (const float*)d_in[6];
    const float* br2 = (const float*)d_in[7];
    const float* Ws2 = (const float*)d_in[8];
    const float* Wr3 = (const float*)d_in[9];
    const float* br3 = (const float*)d_in[10];
    const float* Ws3 = (const float*)d_in[11];
    const float* Wfc1 = (const float*)d_in[12];
    const float* bfc1 = (const float*)d_in[13];
    const float* Wfc2 = (const float*)d_in[14];
    const float* bfc2 = (const float*)d_in[15];

    const int* src = edge;
    const int* dst = edge + N_EDGES;

    // workspace layout (16 B aligned), ~51 MB total
    ushort* Xb     = (ushort*)d_ws;                       // 6.4M bf16 (12.8 MB)
    ushort* Ab     = Xb + (size_t)N_NODES * D;            // 6.4M bf16 (12.8 MB)
    float*  g      = (float*)(Ab + (size_t)N_NODES * D);  // 8192 f
    int*   gcur    = (int*)(g + (size_t)N_GRAPHS * D);    // 392 i
    int*   cnt     = gcur + 392;                          // 100,000 i (binB writes)
    int*   b1      = cnt + N_NODES;                       // 100,000*16 i (6.4 MB)
    int*   b2      = b1 + (size_t)N_NODES * CAPN1;        // 100,000*32 i (12.8 MB)
    int*   cbuf    = b2 + (size_t)N_NODES * CAPN2;        // 391*3584 i (5.6 MB)

    dim3 blk256(256);
    dim3 grdB((int)NBKT);                                 // 391
    dim3 grdT((int)NTILES);                               // 1563

    // ---- zero g + gcur via graph-capturable DMA memset (34.3 KB)
    hipMemsetAsync(g, 0, (size_t)(N_GRAPHS * D + 392) * sizeof(float), stream);

    // ---- fused prep(x->bf16) + binA coarse partition
    prep_binA_kernel<<<dim3(GRID_PB), blk256, 0, stream>>>(x, Xb, src, dst, gcur, cbuf);

    // ---- binB: per-bucket dense scatter
    binB_kernel<<<grdB, blk256, 0, stream>>>(cbuf, gcur, b1, b2, cnt);

    // ---- 3 fused GraphConv layers (layer 3 pools directly into g)
    fused_layer_kernel<0><<<grdT, blk256, 0, stream>>>(Xb, cnt, b1, b2, Wr1, br1, Ws1, Ab, batch, g);
    fused_layer_kernel<0><<<grdT, blk256, 0, stream>>>(Ab, cnt, b1, b2, Wr2, br2, Ws2, Xb, batch, g);
    fused_layer_kernel<1><<<grdT, blk256, 0, stream>>>(Xb, cnt, b1, b2, Wr3, br3, Ws3, Ab, batch, g);

    // ---- head
    head_kernel<<<dim3(N_GRAPHS), dim3(64), 0, stream>>>(g, Wfc1, bfc1, Wfc2, bfc2, (float*)d_out);
}

// Round 20
// 316.616 us; speedup vs baseline: 1.7101x; 1.0576x over previous
//
#include <hip/hip_runtime.h>

#define N_NODES   100000
#define N_EDGES   1200000
#define D         64
#define N_GRAPHS  128
#define N_CLASSES 3

#define TILE      64                               // nodes per tile (layer + bucket)
#define NTILES    ((N_NODES + TILE - 1) / TILE)    // 1563
#define TCAP      1024                             // edges per tile bucket (mean 768, +9.2 sigma)
#define LSTRIDE   68                               // 64 + 4 pad (floats)

#define EPB       8192                             // edges per binA block
#define NEB       ((N_EDGES + EPB - 1) / EPB)      // 147
#define GRID_PB   1024                             // prep+binA fused grid

typedef unsigned int  uint;
typedef unsigned short ushort;

// ------------------------------------------------------------- bf16 helpers
__device__ __forceinline__ ushort bf16_rne(float f) {
    uint u = __float_as_uint(f);
    u += 0x7FFFu + ((u >> 16) & 1u);      // round to nearest even
    return (ushort)(u >> 16);
}
__device__ __forceinline__ void acc8(float* a, uint4 v) {
    a[0] += __uint_as_float(v.x << 16);
    a[1] += __uint_as_float(v.x & 0xFFFF0000u);
    a[2] += __uint_as_float(v.y << 16);
    a[3] += __uint_as_float(v.y & 0xFFFF0000u);
    a[4] += __uint_as_float(v.z << 16);
    a[5] += __uint_as_float(v.z & 0xFFFF0000u);
    a[6] += __uint_as_float(v.w << 16);
    a[7] += __uint_as_float(v.w & 0xFFFF0000u);
}

// gather over one adjacency segment, indices from pointer PT (global or LDS)
template<typename PT>
__device__ __forceinline__ void gather_idx(
        float* acc, PT cp, int len,
        const ushort* __restrict__ hin, int fq8) {
    int j = 0;
    for (; j + 8 <= len; j += 8) {
        int s0 = cp[j + 0], s1 = cp[j + 1], s2 = cp[j + 2], s3 = cp[j + 3];
        int s4 = cp[j + 4], s5 = cp[j + 5], s6 = cp[j + 6], s7 = cp[j + 7];
        uint4 v0 = *(const uint4*)(hin + (size_t)s0 * D + fq8);
        uint4 v1 = *(const uint4*)(hin + (size_t)s1 * D + fq8);
        uint4 v2 = *(const uint4*)(hin + (size_t)s2 * D + fq8);
        uint4 v3 = *(const uint4*)(hin + (size_t)s3 * D + fq8);
        uint4 v4 = *(const uint4*)(hin + (size_t)s4 * D + fq8);
        uint4 v5 = *(const uint4*)(hin + (size_t)s5 * D + fq8);
        uint4 v6 = *(const uint4*)(hin + (size_t)s6 * D + fq8);
        uint4 v7 = *(const uint4*)(hin + (size_t)s7 * D + fq8);
        acc8(acc, v0); acc8(acc, v1); acc8(acc, v2); acc8(acc, v3);
        acc8(acc, v4); acc8(acc, v5); acc8(acc, v6); acc8(acc, v7);
    }
    for (; j + 4 <= len; j += 4) {
        int s0 = cp[j + 0], s1 = cp[j + 1], s2 = cp[j + 2], s3 = cp[j + 3];
        uint4 v0 = *(const uint4*)(hin + (size_t)s0 * D + fq8);
        uint4 v1 = *(const uint4*)(hin + (size_t)s1 * D + fq8);
        uint4 v2 = *(const uint4*)(hin + (size_t)s2 * D + fq8);
        uint4 v3 = *(const uint4*)(hin + (size_t)s3 * D + fq8);
        acc8(acc, v0); acc8(acc, v1); acc8(acc, v2); acc8(acc, v3);
    }
    for (; j < len; ++j) {
        uint4 v = *(const uint4*)(hin + (size_t)cp[j] * D + fq8);
        acc8(acc, v);
    }
}

// --------------------- shared GEMM epilogue (agg in LDS, x from global)
__device__ __forceinline__ void gemm_body(
        const ushort* __restrict__ hin, const float* aggS,
        const float* __restrict__ Wr, const float* __restrict__ br,
        const float* __restrict__ Ws,
        int node0, int tid, float4* cc) {
    const int q  = tid >> 4;
    const int fq = tid & 15;
    const int f4 = fq * 4;
    const int n0 = node0 + 4 * q;
    const float4* Wr4 = (const float4*)Wr;   // Wr4[k*16+fq]
    const float4* Ws4 = (const float4*)Ws;
    const uint* x0p = (const uint*)(hin + (size_t)(n0 + 0) * D);
    const uint* x1p = (const uint*)(hin + (size_t)(n0 + 1) * D);
    const uint* x2p = (const uint*)(hin + (size_t)(n0 + 2) * D);
    const uint* x3p = (const uint*)(hin + (size_t)(n0 + 3) * D);
    float4 bias = *(const float4*)(br + f4);
    float4 c0 = bias, c1 = bias, c2 = bias, c3 = bias;

#pragma unroll 4
    for (int kk = 0; kk < 32; ++kk) {
        const int k0 = 2 * kk;
        float4 wrA = Wr4[k0 * 16 + fq];
        float4 wrB = Wr4[(k0 + 1) * 16 + fq];
        float4 wsA = Ws4[k0 * 16 + fq];
        float4 wsB = Ws4[(k0 + 1) * 16 + fq];
        uint u0 = x0p[kk], u1 = x1p[kk], u2 = x2p[kk], u3 = x3p[kk];
        float2 a0 = *(const float2*)&aggS[(4 * q + 0) * LSTRIDE + k0];
        float2 a1 = *(const float2*)&aggS[(4 * q + 1) * LSTRIDE + k0];
        float2 a2 = *(const float2*)&aggS[(4 * q + 2) * LSTRIDE + k0];
        float2 a3 = *(const float2*)&aggS[(4 * q + 3) * LSTRIDE + k0];
        float x0A = __uint_as_float(u0 << 16), x0B = __uint_as_float(u0 & 0xFFFF0000u);
        float x1A = __uint_as_float(u1 << 16), x1B = __uint_as_float(u1 & 0xFFFF0000u);
        float x2A = __uint_as_float(u2 << 16), x2B = __uint_as_float(u2 & 0xFFFF0000u);
        float x3A = __uint_as_float(u3 << 16), x3B = __uint_as_float(u3 & 0xFFFF0000u);
        c0.x += a0.x * wrA.x + x0A * wsA.x;  c0.y += a0.x * wrA.y + x0A * wsA.y;
        c0.z += a0.x * wrA.z + x0A * wsA.z;  c0.w += a0.x * wrA.w + x0A * wsA.w;
        c0.x += a0.y * wrB.x + x0B * wsB.x;  c0.y += a0.y * wrB.y + x0B * wsB.y;
        c0.z += a0.y * wrB.z + x0B * wsB.z;  c0.w += a0.y * wrB.w + x0B * wsB.w;
        c1.x += a1.x * wrA.x + x1A * wsA.x;  c1.y += a1.x * wrA.y + x1A * wsA.y;
        c1.z += a1.x * wrA.z + x1A * wsA.z;  c1.w += a1.x * wrA.w + x1A * wsA.w;
        c1.x += a1.y * wrB.x + x1B * wsB.x;  c1.y += a1.y * wrB.y + x1B * wsB.y;
        c1.z += a1.y * wrB.z + x1B * wsB.z;  c1.w += a1.y * wrB.w + x1B * wsB.w;
        c2.x += a2.x * wrA.x + x2A * wsA.x;  c2.y += a2.x * wrA.y + x2A * wsA.y;
        c2.z += a2.x * wrA.z + x2A * wsA.z;  c2.w += a2.x * wrA.w + x2A * wsA.w;
        c2.x += a2.y * wrB.x + x2B * wsB.x;  c2.y += a2.y * wrB.y + x2B * wsB.y;
        c2.z += a2.y * wrB.z + x2B * wsB.z;  c2.w += a2.y * wrB.w + x2B * wsB.w;
        c3.x += a3.x * wrA.x + x3A * wsA.x;  c3.y += a3.x * wrA.y + x3A * wsA.y;
        c3.z += a3.x * wrA.z + x3A * wsA.z;  c3.w += a3.x * wrA.w + x3A * wsA.w;
        c3.x += a3.y * wrB.x + x3B * wsB.x;  c3.y += a3.y * wrB.y + x3B * wsB.y;
        c3.z += a3.y * wrB.z + x3B * wsB.z;  c3.w += a3.y * wrB.w + x3B * wsB.w;
    }
    cc[0] = c0; cc[1] = c1; cc[2] = c2; cc[3] = c3;
}

// ---------- fused prep + binA (64-node buckets = layer tiles)
// blocks [0,NEB): partition by dst>>6 (packed: src | (dst&63)<<17)
// blocks [NEB,GRID_PB): x f32->bf16 convert
__global__ __launch_bounds__(256) void prep_binA_kernel(
        const float* __restrict__ x, ushort* __restrict__ Xb,
        const int* __restrict__ src, const int* __restrict__ dst,
        int* __restrict__ gcur, int* __restrict__ cbuf) {
    __shared__ int hist[NTILES];   // 6.25 KB
    __shared__ int pos[NTILES];    // 6.25 KB
    const int tid = threadIdx.x;
    const int bid = blockIdx.x;

    if (bid < NEB) {
        const int e0 = bid * EPB;
        int e1 = e0 + EPB; if (e1 > N_EDGES) e1 = N_EDGES;
        for (int i = tid; i < NTILES; i += 256) hist[i] = 0;
        __syncthreads();
        for (int e = e0 + tid; e < e1; e += 256)
            atomicAdd(&hist[dst[e] >> 6], 1);
        __syncthreads();
        for (int b = tid; b < NTILES; b += 256)
            pos[b] = hist[b] ? atomicAdd(&gcur[b], hist[b]) : 0;
        __syncthreads();
        for (int e = e0 + tid; e < e1; e += 256) {
            int d = dst[e];
            int b = d >> 6;
            int r = atomicAdd(&pos[b], 1);
            if (r < TCAP) cbuf[b * TCAP + r] = src[e] | ((d & 63) << 17);
        }
    } else {
        const int cb  = bid - NEB;
        const int NCB = GRID_PB - NEB;       // 877 convert blocks
        const int nodeF4 = N_NODES * D / 4;
        for (int i = cb * 256 + tid; i < nodeF4; i += NCB * 256) {
            float4 v = ((const float4*)x)[i];
            ushort4 o;
            o.x = bf16_rne(v.x); o.y = bf16_rne(v.y);
            o.z = bf16_rne(v.z); o.w = bf16_rne(v.w);
            ((ushort4*)Xb)[i] = o;
        }
    }
}

// ---------- layer 1 fused with binB: sort tile's edges in LDS, emit dense
// CSR (csr + rptr2 for layers 2/3), gather with LDS-resident indices, GEMM.
// launch_bounds(256,4): proven no-spill envelope.
__global__ __launch_bounds__(256, 4) void layer1_fused_kernel(
        const ushort* __restrict__ hin,
        const int* __restrict__ gcur,
        const int* __restrict__ cbuf,
        int* __restrict__ csr,
        int2* __restrict__ rptr2,
        const float* __restrict__ Wr,
        const float* __restrict__ br,
        const float* __restrict__ Ws,
        ushort* __restrict__ hout) {
    __shared__ int   ebuf[TCAP];            // 4 KB
    __shared__ int   sortedS[TCAP];         // 4 KB
    __shared__ float aggS[TILE * LSTRIDE];  // 17.4 KB
    __shared__ int   ldeg[TILE];
    __shared__ int   lbeg[TILE];
    __shared__ int   lcur[TILE];

    const int tid   = threadIdx.x;
    const int tile  = blockIdx.x;
    const int base  = tile * TCAP;
    const int node0 = tile * TILE;

    int E = gcur[tile]; if (E > TCAP) E = TCAP;
    if (tid < TILE) ldeg[tid] = 0;
    for (int i = tid; i < E; i += 256) ebuf[i] = cbuf[base + i];
    __syncthreads();

    for (int i = tid; i < E; i += 256)
        atomicAdd(&ldeg[(ebuf[i] >> 17) & 63], 1);
    __syncthreads();

    if (tid < TILE) {                       // wave-0 exclusive scan over 64 degrees
        int v = ldeg[tid];
        int s = v;
        for (int off = 1; off < 64; off <<= 1) {
            int u = __shfl_up(s, off, 64);
            if (tid >= off) s += u;
        }
        int beg = s - v;
        lbeg[tid] = beg;
        lcur[tid] = beg;
        int n = node0 + tid;
        if (n < N_NODES) rptr2[n] = make_int2(base + beg, base + beg + v);
    }
    __syncthreads();

    for (int i = tid; i < E; i += 256) {
        int p  = ebuf[i];
        int ld = (p >> 17) & 63;
        int s  = p & 0x1FFFF;
        int q  = atomicAdd(&lcur[ld], 1);
        sortedS[q]    = s;
        csr[base + q] = s;                  // dense, block-owned region
    }
    __syncthreads();

    // ---- gather: indices from LDS
    const int fq8 = (tid & 7) * 8;
    for (int r = 0; r < 2; ++r) {
        int ln = r * 32 + (tid >> 3);
        int n  = node0 + ln;
        float acc[8] = {0.f, 0.f, 0.f, 0.f, 0.f, 0.f, 0.f, 0.f};
        if (n < N_NODES)
            gather_idx(acc, (const int*)&sortedS[lbeg[ln]], ldeg[ln], hin, fq8);
        *(float4*)&aggS[ln * LSTRIDE + fq8]     = make_float4(acc[0], acc[1], acc[2], acc[3]);
        *(float4*)&aggS[ln * LSTRIDE + fq8 + 4] = make_float4(acc[4], acc[5], acc[6], acc[7]);
    }
    __syncthreads();

    float4 cc[4];
    gemm_body(hin, aggS, Wr, br, Ws, node0, tid, cc);

    const int q  = tid >> 4;
    const int f4 = (tid & 15) * 4;
#pragma unroll
    for (int i = 0; i < 4; ++i) {
        int n = node0 + 4 * q + i;
        if (n < N_NODES) {
            ushort4 o;
            o.x = bf16_rne(fmaxf(cc[i].x, 0.f));
            o.y = bf16_rne(fmaxf(cc[i].y, 0.f));
            o.z = bf16_rne(fmaxf(cc[i].z, 0.f));
            o.w = bf16_rne(fmaxf(cc[i].w, 0.f));
            *(ushort4*)(hout + (size_t)n * D + f4) = o;
        }
    }
}

// --------------------------- layers 2/3: gather via dense CSR + rptr2
template<int DO_POOL>
__global__ __launch_bounds__(256, 4) void fused_layer_kernel(
        const ushort* __restrict__ hin,
        const int2* __restrict__ rptr2,
        const int* __restrict__ csr,
        const float* __restrict__ Wr,
        const float* __restrict__ br,
        const float* __restrict__ Ws,
        ushort* __restrict__ hout,
        const int* __restrict__ batch,
        float* __restrict__ g) {
    __shared__ float aggS[TILE * LSTRIDE];   // 17.4 KB
    __shared__ int   bS[TILE];

    const int tid   = threadIdx.x;
    const int node0 = blockIdx.x * TILE;

    if (DO_POOL && tid < TILE) {
        int n = node0 + tid;
        bS[tid] = (n < N_NODES) ? batch[n] : -1;
    }

    const int fq8 = (tid & 7) * 8;
    for (int r = 0; r < 2; ++r) {
        int ln = r * 32 + (tid >> 3);
        int n  = node0 + ln;
        float acc[8] = {0.f, 0.f, 0.f, 0.f, 0.f, 0.f, 0.f, 0.f};
        if (n < N_NODES) {
            int2 be = rptr2[n];
            gather_idx(acc, csr + be.x, be.y - be.x, hin, fq8);
        }
        *(float4*)&aggS[ln * LSTRIDE + fq8]     = make_float4(acc[0], acc[1], acc[2], acc[3]);
        *(float4*)&aggS[ln * LSTRIDE + fq8 + 4] = make_float4(acc[4], acc[5], acc[6], acc[7]);
    }
    __syncthreads();

    float4 cc[4];
    gemm_body(hin, aggS, Wr, br, Ws, node0, tid, cc);

    const int q  = tid >> 4;
    const int f4 = (tid & 15) * 4;

    if (!DO_POOL) {
#pragma unroll
        for (int i = 0; i < 4; ++i) {
            int n = node0 + 4 * q + i;
            if (n < N_NODES) {
                ushort4 o;
                o.x = bf16_rne(fmaxf(cc[i].x, 0.f));
                o.y = bf16_rne(fmaxf(cc[i].y, 0.f));
                o.z = bf16_rne(fmaxf(cc[i].z, 0.f));
                o.w = bf16_rne(fmaxf(cc[i].w, 0.f));
                *(ushort4*)(hout + (size_t)n * D + f4) = o;
            }
        }
    } else {
        __syncthreads();   // everyone done reading aggS
#pragma unroll
        for (int i = 0; i < 4; ++i) {
            float* a = &aggS[(4 * q + i) * LSTRIDE + f4];
            a[0] = fmaxf(cc[i].x, 0.f);
            a[1] = fmaxf(cc[i].y, 0.f);
            a[2] = fmaxf(cc[i].z, 0.f);
            a[3] = fmaxf(cc[i].w, 0.f);
        }
        __syncthreads();
        int f    = tid & 63;
        int part = tid >> 6;
        int ln0  = part * 16;
        int cur  = bS[ln0];
        float acc = 0.f;
        for (int ln = ln0; ln < ln0 + 16; ++ln) {
            int b = bS[ln];
            if (b < 0) break;
            if (b != cur) {
                atomicAdd(&g[cur * D + f], acc);
                acc = 0.f;
                cur = b;
            }
            acc += aggS[ln * LSTRIDE + f];
        }
        if (cur >= 0) atomicAdd(&g[cur * D + f], acc);
    }
}

// ------------------------------------------------------------------- MLP head
__global__ __launch_bounds__(64) void head_kernel(
        const float* __restrict__ g,
        const float* __restrict__ Wfc1, const float* __restrict__ bfc1,
        const float* __restrict__ Wfc2, const float* __restrict__ bfc2,
        float* __restrict__ out) {
    __shared__ float hS[D];
    __shared__ float lS[N_CLASSES];
    int gr = blockIdx.x;
    int f  = threadIdx.x;

    float acc = bfc1[f];
#pragma unroll
    for (int k = 0; k < D; ++k) acc += g[gr * D + k] * Wfc1[k * D + f];
    hS[f] = fmaxf(acc, 0.f);
    __syncthreads();

    if (f < N_CLASSES) {
        float a = bfc2[f];
#pragma unroll
        for (int k = 0; k < D; ++k) a += hS[k] * Wfc2[k * N_CLASSES + f];
        lS[f] = a;
    }
    __syncthreads();

    if (f == 0) {
        float m = fmaxf(lS[0], fmaxf(lS[1], lS[2]));
        float s = expf(lS[0] - m) + expf(lS[1] - m) + expf(lS[2] - m);
        float lse = m + logf(s);
        out[gr * 3 + 0] = lS[0] - lse;
        out[gr * 3 + 1] = lS[1] - lse;
        out[gr * 3 + 2] = lS[2] - lse;
    }
}

// ---------------------------------------------------------------------- launch
extern "C" void kernel_launch(void* const* d_in, const int* in_sizes, int n_in,
                              void* d_out, int out_size, void* d_ws, size_t ws_size,
                              hipStream_t stream) {
    const float* x     = (const float*)d_in[0];
    const int*   edge  = (const int*)d_in[1];
    const int*   batch = (const int*)d_in[2];
    const float* Wr1 = (const float*)d_in[3];
    const float* br1 = (const float*)d_in[4];
    const float* Ws1 = (const float*)d_in[5];
    const float* Wr2 = (const float*)d_in[6];
    const float* br2 = (const float*)d_in[7];
    const float* Ws2 = (const float*)d_in[8];
    const float* Wr3 = (const float*)d_in[9];
    const float* br3 = (const float*)d_in[10];
    const float* Ws3 = (const float*)d_in[11];
    const float* Wfc1 = (const float*)d_in[12];
    const float* bfc1 = (const float*)d_in[13];
    const float* Wfc2 = (const float*)d_in[14];
    const float* bfc2 = (const float*)d_in[15];

    const int* src = edge;
    const int* dst = edge + N_EDGES;

    // workspace layout (16 B aligned), ~39.3 MB total
    ushort* Xb     = (ushort*)d_ws;                       // 6.4M bf16 (12.8 MB)
    ushort* Ab     = Xb + (size_t)N_NODES * D;            // 6.4M bf16 (12.8 MB)
    float*  g      = (float*)(Ab + (size_t)N_NODES * D);  // 8192 f
    int*   gcur    = (int*)(g + (size_t)N_GRAPHS * D);    // 1564 i (zeroed w/ g)
    int2*  rptr2   = (int2*)(gcur + 1564);                // 100,000 int2 (0.8 MB)
    int*   cbuf    = (int*)(rptr2 + N_NODES);             // 1563*1024 i (6.4 MB)
    int*   csr     = cbuf + (size_t)NTILES * TCAP;        // 1563*1024 i (6.4 MB)

    dim3 blk256(256);
    dim3 grdT((int)NTILES);                               // 1563

    // ---- zero g + gcur via graph-capturable DMA memset
    hipMemsetAsync(g, 0, (size_t)(N_GRAPHS * D + 1564) * sizeof(float), stream);

    // ---- fused prep(x->bf16) + binA partition into 64-node tile buckets
    prep_binA_kernel<<<dim3(GRID_PB), blk256, 0, stream>>>(x, Xb, src, dst, gcur, cbuf);

    // ---- layer 1 (fused with per-tile edge sort; emits csr + rptr2)
    layer1_fused_kernel<<<grdT, blk256, 0, stream>>>(Xb, gcur, cbuf, csr, rptr2,
                                                     Wr1, br1, Ws1, Ab);

    // ---- layers 2,3 (dense CSR; layer 3 pools into g)
    fused_layer_kernel<0><<<grdT, blk256, 0, stream>>>(Ab, rptr2, csr, Wr2, br2, Ws2, Xb, batch, g);
    fused_layer_kernel<1><<<grdT, blk256, 0, stream>>>(Xb, rptr2, csr, Wr3, br3, Ws3, Ab, batch, g);

    // ---- head
    head_kernel<<<dim3(N_GRAPHS), dim3(64), 0, stream>>>(g, Wfc1, bfc1, Wfc2, bfc2, (float*)d_out);
}